// Round 1
// baseline (65.530 us; speedup 1.0000x reference)
//
#include <hip/hip_runtime.h>
#include <hip/hip_bf16.h>
#include <math.h>

#define NB 8
#define NL 128
#define D_ATOM 256
#define DH 32       // d_hid
#define DAB 64      // 2*d_hid
#define K1 21
#define K2 30
#define KT 51       // K1+K2
#define ROWS (NB*NL) // 1024
#define LN_EPS 1e-5f

// Kernel A: per row (b,l): ab = LN(gelu(z@W_in + b_in)); split into a (first 32) / b (last 32)
__global__ __launch_bounds__(64) void ln_proj_kernel(
    const float* __restrict__ z, const float* __restrict__ W_in,
    const float* __restrict__ b_in, const float* __restrict__ ln_g,
    const float* __restrict__ ln_b, float* __restrict__ a_out,
    float* __restrict__ b_out)
{
    const int row = blockIdx.x;   // b*NL + l
    const int j   = threadIdx.x;  // 0..63 -> output column

    __shared__ float z_lds[D_ATOM];
    for (int i = j; i < D_ATOM; i += 64) z_lds[i] = z[row * D_ATOM + i];
    __syncthreads();

    float acc = b_in[j];
    #pragma unroll 8
    for (int i = 0; i < D_ATOM; ++i)
        acc = fmaf(z_lds[i], W_in[i * DAB + j], acc);

    // exact gelu: x * 0.5 * (1 + erf(x/sqrt(2)))
    float g = 0.5f * acc * (1.0f + erff(acc * 0.70710678118654752f));

    // wave-level (64-lane) reduction for mean / var
    float s = g, sq = g * g;
    #pragma unroll
    for (int m = 1; m < 64; m <<= 1) {
        s  += __shfl_xor(s,  m, 64);
        sq += __shfl_xor(sq, m, 64);
    }
    float mu  = s  * (1.0f / 64.0f);
    float var = sq * (1.0f / 64.0f) - mu * mu;
    float y = (g - mu) * rsqrtf(var + LN_EPS) * ln_g[j] + ln_b[j];

    if (j < DH) a_out[row * DH + j]        = y;
    else        b_out[row * DH + (j - DH)] = y;
}

// Kernel B: per row (b,l):
//   T[d][k] = sum_c a[row][c] * Wr[c][d][k]        (k in [0,51): 21 from W1, 30 from W2)
//   out[row][m][k] = sum_d T[d][k] * b[batch][m][d] + bias[k]
__global__ __launch_bounds__(256) void pair_proj_kernel(
    const float* __restrict__ a_g, const float* __restrict__ b_g,
    const float* __restrict__ W1, const float* __restrict__ b1,
    const float* __restrict__ W2, const float* __restrict__ b2,
    float* __restrict__ out)
{
    const int row   = blockIdx.x;   // b*NL + l
    const int batch = row >> 7;     // row / 128
    const int t     = threadIdx.x;  // 0..255

    __shared__ float a_lds[DH];
    __shared__ float bb_lds[NL][DH + 1];   // +1 pad: kill stride-32 bank conflict
    __shared__ float T_lds[DH][KT + 1];    // +1 pad

    if (t < DH) a_lds[t] = a_g[row * DH + t];
    for (int idx = t; idx < NL * DH; idx += 256) {
        int m = idx >> 5, d = idx & 31;
        bb_lds[m][d] = b_g[batch * NL * DH + idx];
    }
    __syncthreads();

    // T[d][k] = sum_c a[c] * W(c*32+d, k)
    for (int o = t; o < DH * KT; o += 256) {
        int d = o / KT, k = o % KT;
        float acc = 0.f;
        if (k < K1) {
            const float* w = W1 + d * K1 + k;
            #pragma unroll
            for (int c = 0; c < DH; ++c) acc = fmaf(a_lds[c], w[c * DH * K1], acc);
        } else {
            const float* w = W2 + d * K2 + (k - K1);
            #pragma unroll
            for (int c = 0; c < DH; ++c) acc = fmaf(a_lds[c], w[c * DH * K2], acc);
        }
        T_lds[d][k] = acc;
    }
    __syncthreads();

    const size_t base1 = (size_t)row * NL * K1;
    const size_t base2 = (size_t)ROWS * NL * K1 + (size_t)row * NL * K2;

    for (int o = t; o < NL * KT; o += 256) {
        int m = o / KT, k = o % KT;
        float r = 0.f;
        #pragma unroll
        for (int d = 0; d < DH; ++d)
            r = fmaf(bb_lds[m][d], T_lds[d][k], r);
        if (k < K1) out[base1 + (size_t)m * K1 + k]        = r + b1[k];
        else        out[base2 + (size_t)m * K2 + (k - K1)] = r + b2[k - K1];
    }
}

extern "C" void kernel_launch(void* const* d_in, const int* in_sizes, int n_in,
                              void* d_out, int out_size, void* d_ws, size_t ws_size,
                              hipStream_t stream) {
    const float* z    = (const float*)d_in[0];
    const float* W_in = (const float*)d_in[1];
    const float* b_in = (const float*)d_in[2];
    const float* ln_g = (const float*)d_in[3];
    const float* ln_b = (const float*)d_in[4];
    const float* W1   = (const float*)d_in[5];
    const float* b1   = (const float*)d_in[6];
    const float* W2   = (const float*)d_in[7];
    const float* b2   = (const float*)d_in[8];
    float* out = (float*)d_out;

    float* a_ws = (float*)d_ws;            // ROWS*DH floats
    float* b_ws = a_ws + ROWS * DH;        // ROWS*DH floats (total 256 KB)

    ln_proj_kernel<<<ROWS, 64, 0, stream>>>(z, W_in, b_in, ln_g, ln_b, a_ws, b_ws);
    pair_proj_kernel<<<ROWS, 256, 0, stream>>>(a_ws, b_ws, W1, b1, W2, b2, out);
}

// Round 2
// 36.806 us; speedup vs baseline: 1.7804x; 1.7804x over previous
//
#include <hip/hip_runtime.h>
#include <hip/hip_bf16.h>
#include <math.h>

#define NB 8
#define NL 128
#define D_ATOM 256
#define DH 32       // d_hid
#define DAB 64      // 2*d_hid
#define K1 21
#define K2 30
#define KT 51       // K1+K2
#define ROWS (NB*NL) // 1024
#define LN_EPS 1e-5f

#define BBT_STRIDE (NL + 8)   // 136 floats: rows 544B (16B-aligned), banks spread
#define T_STRIDE 52           // padded K; 208B rows, 16B-aligned

// Kernel A: 4 rows per block, one wave per row.
// ab = LN(gelu(z@W_in + b_in)); split into a (first 32) / b (last 32)
__global__ __launch_bounds__(256) void ln_proj_kernel(
    const float* __restrict__ z, const float* __restrict__ W_in,
    const float* __restrict__ b_in, const float* __restrict__ ln_g,
    const float* __restrict__ ln_b, float* __restrict__ a_out,
    float* __restrict__ b_out)
{
    const int wid = threadIdx.x >> 6;          // wave id 0..3
    const int j   = threadIdx.x & 63;          // output column
    const int row = blockIdx.x * 4 + wid;

    __shared__ float z_lds[4][D_ATOM];
    #pragma unroll
    for (int s = 0; s < 4; ++s) z_lds[wid][j + s * 64] = z[row * D_ATOM + j + s * 64];
    __syncthreads();

    float acc = b_in[j];
    #pragma unroll 8
    for (int i = 0; i < D_ATOM; ++i)
        acc = fmaf(z_lds[wid][i], W_in[i * DAB + j], acc);

    // exact gelu: x * 0.5 * (1 + erf(x/sqrt(2)))
    float g = 0.5f * acc * (1.0f + erff(acc * 0.70710678118654752f));

    float s = g, sq = g * g;
    #pragma unroll
    for (int m = 1; m < 64; m <<= 1) {
        s  += __shfl_xor(s,  m, 64);
        sq += __shfl_xor(sq, m, 64);
    }
    float mu  = s  * (1.0f / 64.0f);
    float var = sq * (1.0f / 64.0f) - mu * mu;
    float y = (g - mu) * rsqrtf(var + LN_EPS) * ln_g[j] + ln_b[j];

    if (j < DH) a_out[row * DH + j]        = y;
    else        b_out[row * DH + (j - DH)] = y;
}

// Kernel B: 2 rows (same batch) per block, 256 threads.
// Phase 1: T_r[d][k] = sum_c a[r][c] * Wr[c,d,k]  (inline, coalesced W reads)
// Phase 2: out[r][m][k] = sum_d bbT[d][m] * T_r[d][k] + bias[k]
//          register tile: 8 m x 4 k x 2 rows per thread (208 active threads)
__global__ __launch_bounds__(256) void pair_proj_kernel(
    const float* __restrict__ a_g, const float* __restrict__ b_g,
    const float* __restrict__ W1, const float* __restrict__ b1v,
    const float* __restrict__ W2, const float* __restrict__ b2v,
    float* __restrict__ out)
{
    const int row0  = blockIdx.x * 2;
    const int batch = row0 >> 7;
    const int t     = threadIdx.x;

    __shared__ float a_lds[2][DH];
    __shared__ float bbT[DH][BBT_STRIDE];       // [d][m] transposed
    __shared__ float T_lds[2][DH * T_STRIDE];   // [r][d*52+k]

    // --- stage a rows + transposed bb ---
    if (t < 2 * DH) a_lds[t >> 5][t & 31] = a_g[row0 * DH + t];
    #pragma unroll
    for (int s = 0; s < 16; ++s) {
        int idx = t + s * 256;                  // idx = m*32 + d
        int m = idx >> 5, d = idx & 31;
        bbT[d][m] = b_g[batch * NL * DH + idx];
    }
    __syncthreads();

    // --- phase 1: inline T compute, coalesced W reads ---
    // Wcat row for c = [W1[c*672 .. +672) | W2[c*960 .. +960)], 1632 cols total.
    float tacc0[7], tacc1[7];
    const float* wptr[7];
    int wstr[7], tidx[7];
    bool val[7];
    #pragma unroll
    for (int s = 0; s < 7; ++s) {
        int o = t + s * 256;
        val[s] = (o < 1632);
        int oo = val[s] ? o : 0;
        if (oo < 672) {
            wptr[s] = W1 + oo; wstr[s] = 672;
            int d = oo / 21, k = oo % 21;
            tidx[s] = d * T_STRIDE + k;
        } else {
            int o2 = oo - 672;
            wptr[s] = W2 + o2; wstr[s] = 960;
            int d = o2 / 30, k = 21 + o2 % 30;
            tidx[s] = d * T_STRIDE + k;
        }
        tacc0[s] = 0.f; tacc1[s] = 0.f;
    }
    #pragma unroll 4
    for (int c = 0; c < DH; ++c) {
        float ac0 = a_lds[0][c], ac1 = a_lds[1][c];
        #pragma unroll
        for (int s = 0; s < 7; ++s) {
            float w = wptr[s][c * wstr[s]];
            tacc0[s] = fmaf(ac0, w, tacc0[s]);
            tacc1[s] = fmaf(ac1, w, tacc1[s]);
        }
    }
    #pragma unroll
    for (int s = 0; s < 7; ++s) {
        if (val[s]) { T_lds[0][tidx[s]] = tacc0[s]; T_lds[1][tidx[s]] = tacc1[s]; }
    }
    if (t < DH) { T_lds[0][t * T_STRIDE + 51] = 0.f; T_lds[1][t * T_STRIDE + 51] = 0.f; }
    __syncthreads();

    // --- phase 2: register-tiled pair product ---
    if (t < 208) {
        const int mt = t / 13, kt = t % 13;
        const int m0 = mt * 8, k0 = kt * 4;

        float acc[2][8][4];
        #pragma unroll
        for (int r = 0; r < 2; ++r)
            #pragma unroll
            for (int i = 0; i < 8; ++i)
                #pragma unroll
                for (int jj = 0; jj < 4; ++jj) acc[r][i][jj] = 0.f;

        #pragma unroll 4
        for (int d = 0; d < DH; ++d) {
            float4 bv0 = *(const float4*)&bbT[d][m0];
            float4 bv1 = *(const float4*)&bbT[d][m0 + 4];
            float4 t0  = *(const float4*)&T_lds[0][d * T_STRIDE + k0];
            float4 t1  = *(const float4*)&T_lds[1][d * T_STRIDE + k0];
            float bv[8] = {bv0.x, bv0.y, bv0.z, bv0.w, bv1.x, bv1.y, bv1.z, bv1.w};
            float tv0[4] = {t0.x, t0.y, t0.z, t0.w};
            float tv1[4] = {t1.x, t1.y, t1.z, t1.w};
            #pragma unroll
            for (int i = 0; i < 8; ++i) {
                #pragma unroll
                for (int jj = 0; jj < 4; ++jj) {
                    acc[0][i][jj] = fmaf(bv[i], tv0[jj], acc[0][i][jj]);
                    acc[1][i][jj] = fmaf(bv[i], tv1[jj], acc[1][i][jj]);
                }
            }
        }

        float bias[4];
        bool kvalid[4];
        #pragma unroll
        for (int jj = 0; jj < 4; ++jj) {
            int k = k0 + jj;
            kvalid[jj] = (k < KT);
            bias[jj] = (k < K1) ? b1v[k] : (k < KT ? b2v[k - K1] : 0.f);
        }

        #pragma unroll
        for (int r = 0; r < 2; ++r) {
            const int row = row0 + r;
            float* o1 = out + (size_t)row * NL * K1;
            float* o2 = out + (size_t)ROWS * NL * K1 + (size_t)row * NL * K2;
            #pragma unroll
            for (int i = 0; i < 8; ++i) {
                const int m = m0 + i;
                #pragma unroll
                for (int jj = 0; jj < 4; ++jj) {
                    if (!kvalid[jj]) continue;
                    const int k = k0 + jj;
                    float v = acc[r][i][jj] + bias[jj];
                    if (k < K1) o1[m * K1 + k]        = v;
                    else        o2[m * K2 + (k - K1)] = v;
                }
            }
        }
    }
}

extern "C" void kernel_launch(void* const* d_in, const int* in_sizes, int n_in,
                              void* d_out, int out_size, void* d_ws, size_t ws_size,
                              hipStream_t stream) {
    const float* z    = (const float*)d_in[0];
    const float* W_in = (const float*)d_in[1];
    const float* b_in = (const float*)d_in[2];
    const float* ln_g = (const float*)d_in[3];
    const float* ln_b = (const float*)d_in[4];
    const float* W1   = (const float*)d_in[5];
    const float* b1   = (const float*)d_in[6];
    const float* W2   = (const float*)d_in[7];
    const float* b2   = (const float*)d_in[8];
    float* out = (float*)d_out;

    float* a_ws = (float*)d_ws;            // ROWS*DH floats
    float* b_ws = a_ws + ROWS * DH;        // ROWS*DH floats (total 256 KB)

    ln_proj_kernel<<<ROWS / 4, 256, 0, stream>>>(z, W_in, b_in, ln_g, ln_b, a_ws, b_ws);
    pair_proj_kernel<<<ROWS / 2, 256, 0, stream>>>(a_ws, b_ws, W1, b1, W2, b2, out);
}